// Round 9
// baseline (406.912 us; speedup 1.0000x reference)
//
#include <hip/hip_runtime.h>
#include <hip/hip_bf16.h>
#include <stdint.h>

// Problem constants
#define B_N   2048
#define XW    128      // x row width (real 64 | meta 64)
#define KDIM  512      // W_out column count (= H)
#define NROWS_W   66112
#define NROWS_PAD 66560   // padded bf16-W rows (stage3 tile 129 reaches 66560)

typedef __bf16 v8bf  __attribute__((ext_vector_type(8)));
typedef float  f32x4 __attribute__((ext_vector_type(4)));

__device__ __forceinline__ unsigned short f2bf(float f) {
    uint32_t u = __float_as_uint(f);
    u += 0x7FFF + ((u >> 16) & 1);          // round-to-nearest-even
    return (unsigned short)(u >> 16);
}
__device__ __forceinline__ float bf2f(unsigned short h) {
    return __uint_as_float(((uint32_t)h) << 16);
}
__device__ __forceinline__ float elu1(float v) {
    return v > 0.0f ? v : expm1f(v);
}
__device__ __forceinline__ void gload_lds16(const void* g, void* l) {
    __builtin_amdgcn_global_load_lds(
        (const __attribute__((address_space(1))) unsigned int*)g,
        (__attribute__((address_space(3))) unsigned int*)l, 16, 0, 0);
}

// ---------------- K1: h = elu(meta @ W_in^T + b_in), stored bf16 ----------------
__global__ void k_h(const float* __restrict__ x, const float* __restrict__ W_in,
                    const float* __restrict__ b_in, unsigned short* __restrict__ hb) {
    int idx = blockIdx.x * 256 + threadIdx.x;      // b*512 + j
    int b = idx >> 9, j = idx & 511;
    const float4* xm = (const float4*)(x + (size_t)b * XW + 64);
    const float4* wr = (const float4*)(W_in + (size_t)j * 64);
    float acc = 0.f;
#pragma unroll
    for (int q = 0; q < 16; ++q) {
        float4 a = xm[q], w = wr[q];
        acc += a.x * w.x + a.y * w.y + a.z * w.z + a.w * w.w;
    }
    acc = elu1(acc + b_in[j]);
    hb[idx] = f2bf(acc);
}

// ---------------- K-conv: W_out f32 -> bf16 (padded rows zeroed) ---------------
__global__ void k_conv(const float* __restrict__ Wf, unsigned short* __restrict__ Wb) {
    size_t c = (size_t)blockIdx.x * 256 + threadIdx.x;  // 8-elem chunk id
    size_t row = c >> 6; int kk = (int)(c & 63);
    union { uint4 v; unsigned short u[8]; } o;
    o.v = (uint4){0, 0, 0, 0};
    if (row < NROWS_W) {
        const float* wp = Wf + row * KDIM + kk * 8;
        float4 w0 = *(const float4*)wp, w1 = *(const float4*)(wp + 4);
        o.u[0] = f2bf(w0.x); o.u[1] = f2bf(w0.y); o.u[2] = f2bf(w0.z); o.u[3] = f2bf(w0.w);
        o.u[4] = f2bf(w1.x); o.u[5] = f2bf(w1.y); o.u[6] = f2bf(w1.z); o.u[7] = f2bf(w1.w);
    }
    *(uint4*)(Wb + c * 8) = o.v;
}

// ---------------- K-init-ypre: ypre = b_out[32768+hh] + sum_i real_i*b_out[i*512+hh]
__global__ void k_init_ypre(const float* __restrict__ x, const float* __restrict__ b_out,
                            float* __restrict__ ypre) {
    int idx = blockIdx.x * 256 + threadIdx.x;   // b*512 + hh
    int b = idx >> 9, hh = idx & 511;
    float acc = b_out[32768 + hh];
    const float* xr = x + (size_t)b * XW;       // real part
#pragma unroll 8
    for (int i = 0; i < 64; ++i)
        acc += xr[i] * b_out[i * 512 + hh];
    ypre[idx] = acc;
}

// ---------------- K-y: yv = elu(ypre) ------------------------------------------
__global__ void k_y(const float* __restrict__ ypre, float* __restrict__ yv) {
    int idx = blockIdx.x * 256 + threadIdx.x;
    yv[idx] = elu1(ypre[idx]);
}

// ---------------- K-init-out: out = b_out[66048+o] + sum_hh yv*b_out[33280+hh*64+o]
__global__ void k_init_out(const float* __restrict__ yv, const float* __restrict__ b_out,
                           float* __restrict__ out) {
    int idx = blockIdx.x * 256 + threadIdx.x;   // b*64 + o
    int b = idx >> 6, o = idx & 63;
    float acc = b_out[66048 + o];
    const float* yr = yv + (size_t)b * 512;
#pragma unroll 4
    for (int hh = 0; hh < 512; ++hh)
        acc += yr[hh] * b_out[33280 + hh * 64 + o];
    out[idx] = acc;
}

// ---------------- panel GEMM: 256x256 tile, K-outer/panel-inner, big groups ----
// Both stages: 130 N-tiles of 256 W-rows, 26 splits x 5 tiles (uniform).
// MODE0: tile t = par*65+i -> W rows i*512+par*256, outcol par*256+c, s=real[b,i]
//        (i==64 -> l_in_b, s=1). Split s<13 par0, s>=13 par1 (65=13*5 exact).
// MODE1: tile t -> W rows 33280+t*256, outcol c&63, s=yv[b, t*4+(c>>6)]
//        (group>=512 -> 1; pad rows zero). 8 waves 2Mx4N, wave-tile 128x64.
// LDS: A 2x32KB (K-pair, staged once per ktp) + B dbuf 2x32KB + bf16 scales.
// Group = (ktL, panel): {vmcnt(0); barrier; issue next B-stage; 8 B-frag reads;
// 4 quadrant-phases: 4 A-reads + 16 MFMA + scale-fold into accO}. 1 barrier/grp.
template<int MODE>
__global__ __launch_bounds__(512, 2)
void k_pgemm(const unsigned short* __restrict__ hb,
             const unsigned short* __restrict__ Wb,
             const float* __restrict__ scaleSrc,
             float* __restrict__ outAcc) {
    constexpr int SCN = MODE ? 5 * 4 * 256 : 5 * 256;

    __shared__ char smem[131072 + SCN * 2];
    char* As = smem;                      // 2 x [256][64] bf16, swizzled
    char* Bs = smem + 65536;              // 2 x [256][64] bf16, swizzled
    unsigned short* scb = (unsigned short*)(smem + 131072);

    const int bid = blockIdx.x;           // 0..207
    const int m0  = (bid & 7) * 256;
    const int s   = bid >> 3;             // split 0..25
    const int par = (MODE == 0) ? (s >= 13 ? 1 : 0) : 0;
    const int tBase = s * 5;

    const int tid = threadIdx.x;
    const int wid = tid >> 6, l = tid & 63;
    const int lr = l & 15, lg = l >> 4;
    const int wm = wid >> 2, wn = wid & 3;          // wave grid 2M x 4N

    // ---- stage scales (bf16) ----
    for (int c = tid; c < SCN; c += 512) {
        float v = 1.0f;
        if (MODE == 0) {
            int p = c >> 8, row = c & 255;
            int i = tBase + p - par * 65;
            if (i < 64) v = scaleSrc[(size_t)(m0 + row) * XW + i];
        } else {
            int p = c >> 10, g4 = (c >> 8) & 3, row = c & 255;
            int gg = (tBase + p) * 4 + g4;
            if (gg < 512) v = scaleSrc[(size_t)(m0 + row) * KDIM + gg];
        }
        scb[c] = f2bf(v);
    }
    __syncthreads();

    // staging constants: 32KB tile = 4 chunks; row=qc*64+(tid>>3), slot=tid&7
    const int srow = tid >> 3;
    const int k8p  = (tid & 7) ^ ((tid >> 3) & 7);   // inverse read-swizzle
    const unsigned short* hbB = hb + (size_t)m0 * KDIM;

    // per-wave read bases
    int aRow[8], bRow[4];
#pragma unroll
    for (int mi = 0; mi < 8; ++mi) aRow[mi] = wm * 128 + mi * 16 + lr;
#pragma unroll
    for (int ni = 0; ni < 4; ++ni) bRow[ni] = wn * 64 + ni * 16 + lr;
    const int scBase = wm * 128 + lg * 4;

    f32x4 accO[8][4];
#pragma unroll
    for (int mi = 0; mi < 8; ++mi)
#pragma unroll
        for (int ni = 0; ni < 4; ++ni) accO[mi][ni] = (f32x4){0.f, 0.f, 0.f, 0.f};

    // W-row bases per panel
    int wrB[5];
#pragma unroll
    for (int p = 0; p < 5; ++p) {
        int t = tBase + p;
        wrB[p] = MODE ? (33280 + t * 256) : ((t - par * 65) * 512 + par * 256);
    }

    for (int ktp = 0; ktp < 4; ++ktp) {
        // ---- ktp prologue: drain, close reads, stage A(both kt) + B(group 0) ----
        asm volatile("s_waitcnt vmcnt(0)" ::: "memory");
        __builtin_amdgcn_s_barrier();
        asm volatile("" ::: "memory");
#pragma unroll
        for (int ktL = 0; ktL < 2; ++ktL)
#pragma unroll
            for (int qc = 0; qc < 4; ++qc)
                gload_lds16(hbB + (size_t)(qc * 64 + srow) * KDIM + ktp * 128 + ktL * 64 + k8p * 8,
                            As + ktL * 32768 + qc * 8192 + tid * 16);
#pragma unroll
        for (int qc = 0; qc < 4; ++qc)
            gload_lds16(Wb + (size_t)(wrB[0] + qc * 64 + srow) * KDIM + ktp * 128 + k8p * 8,
                        Bs + qc * 8192 + tid * 16);

#pragma unroll
        for (int ktL = 0; ktL < 2; ++ktL) {
#pragma unroll
            for (int p = 0; p < 5; ++p) {
                const int g = ktL * 5 + p;
                asm volatile("s_waitcnt vmcnt(0)" ::: "memory");
                __builtin_amdgcn_s_barrier();
                asm volatile("" ::: "memory");
                // issue next B-stage (within this ktp)
                if (g < 9) {
                    const int nktL = (p == 4) ? ktL + 1 : ktL;
                    const int np   = (p == 4) ? 0 : p + 1;
                    char* dB = Bs + ((g + 1) & 1) * 32768;
#pragma unroll
                    for (int qc = 0; qc < 4; ++qc)
                        gload_lds16(Wb + (size_t)(wrB[np] + qc * 64 + srow) * KDIM
                                       + ktp * 128 + nktL * 64 + k8p * 8,
                                    dB + qc * 8192 + tid * 16);
                }
                const char* Bbuf = Bs + (g & 1) * 32768;
                const char* Abuf = As + ktL * 32768;
                // ---- read all 8 B fragments once ----
                v8bf bfr[4][2];
#pragma unroll
                for (int ni = 0; ni < 4; ++ni)
#pragma unroll
                    for (int ks = 0; ks < 2; ++ks)
                        bfr[ni][ks] = *(const v8bf*)(Bbuf + bRow[ni] * 128
                                      + (((ks * 4 + lg) ^ (bRow[ni] & 7)) << 4));
                const int scOff = MODE ? ((p * 4 + wn) * 256 + scBase) : (p * 256 + scBase);
                __builtin_amdgcn_s_setprio(1);
#pragma unroll
                for (int q = 0; q < 4; ++q) {
#pragma unroll
                    for (int mi2 = 0; mi2 < 2; ++mi2) {
                        const int mi = q * 2 + mi2;
                        v8bf a0 = *(const v8bf*)(Abuf + aRow[mi] * 128
                                   + (((0 + lg) ^ (aRow[mi] & 7)) << 4));
                        v8bf a1 = *(const v8bf*)(Abuf + aRow[mi] * 128
                                   + (((4 + lg) ^ (aRow[mi] & 7)) << 4));
                        ushort4 su = *(const ushort4*)(scb + scOff + mi * 16);
                        f32x4 sv = {bf2f(su.x), bf2f(su.y), bf2f(su.z), bf2f(su.w)};
#pragma unroll
                        for (int ni = 0; ni < 4; ++ni) {
                            f32x4 t = __builtin_amdgcn_mfma_f32_16x16x32_bf16(
                                a0, bfr[ni][0], (f32x4){0.f, 0.f, 0.f, 0.f}, 0, 0, 0);
                            t = __builtin_amdgcn_mfma_f32_16x16x32_bf16(
                                a1, bfr[ni][1], t, 0, 0, 0);
                            accO[mi][ni] += sv * t;
                        }
                    }
                }
                __builtin_amdgcn_s_setprio(0);
            }
        }
    }

    // ---- epilogue ----
    if (MODE == 0) {
#pragma unroll
        for (int mi = 0; mi < 8; ++mi)
#pragma unroll
            for (int ni = 0; ni < 4; ++ni)
#pragma unroll
                for (int r = 0; r < 4; ++r) {
                    int row = m0 + wm * 128 + mi * 16 + lg * 4 + r;
                    int col = par * 256 + wn * 64 + ni * 16 + lr;
                    atomicAdd(outAcc + (size_t)row * KDIM + col, accO[mi][ni][r]);
                }
    } else {
        // cross-wave (wn) reduce in LDS, then atomics into out[2048][64]
        float* red = (float*)smem;           // 256 x 64 f32 = 64KB (reuse A)
        __builtin_amdgcn_s_barrier();
        asm volatile("" ::: "memory");
#pragma unroll
        for (int rnd = 0; rnd < 4; ++rnd) {
            if (wn == rnd) {
#pragma unroll
                for (int mi = 0; mi < 8; ++mi)
#pragma unroll
                    for (int ni = 0; ni < 4; ++ni)
#pragma unroll
                        for (int r = 0; r < 4; ++r) {
                            int idx = (wm * 128 + mi * 16 + lg * 4 + r) * 64 + ni * 16 + lr;
                            if (rnd == 0) red[idx] = accO[mi][ni][r];
                            else          red[idx] += accO[mi][ni][r];
                        }
            }
            __builtin_amdgcn_s_barrier();
            asm volatile("" ::: "memory");
        }
#pragma unroll
        for (int jj = 0; jj < 32; ++jj) {
            int flat = jj * 512 + tid;
            atomicAdd(outAcc + (size_t)(m0 + (flat >> 6)) * 64 + (flat & 63), red[flat]);
        }
    }
}

extern "C" void kernel_launch(void* const* d_in, const int* in_sizes, int n_in,
                              void* d_out, int out_size, void* d_ws, size_t ws_size,
                              hipStream_t stream) {
    const float* x     = (const float*)d_in[0];
    const float* W_in  = (const float*)d_in[1];
    const float* b_in  = (const float*)d_in[2];
    const float* W_out = (const float*)d_in[3];
    const float* b_out = (const float*)d_in[4];
    float* out = (float*)d_out;

    char* ws = (char*)d_ws;
    unsigned short* hb = (unsigned short*)ws;            // 2 MB  h bf16
    float* ypre        = (float*)(ws + (2u << 20));      // 4 MB
    float* yv          = (float*)(ws + (6u << 20));      // 4 MB  yv = elu(ypre)
    unsigned short* Wb = (unsigned short*)(ws + (10u << 20));  // 68.2 MB bf16 W_out

    k_h<<<(B_N * 512) / 256, 256, 0, stream>>>(x, W_in, b_in, hb);
    k_conv<<<((size_t)NROWS_PAD * KDIM / 8) / 256, 256, 0, stream>>>(W_out, Wb);

    // ypre := bias terms (l_in_b bias + real-weighted l_in_w biases)
    k_init_ypre<<<(B_N * 512) / 256, 256, 0, stream>>>(x, b_out, ypre);

    // Stage 2: ypre += sum_i real_i * (h @ W_i^T)
    k_pgemm<0><<<208, 512, 0, stream>>>(hb, Wb, x, ypre);

    // yv := elu(ypre)
    k_y<<<(B_N * 512) / 256, 256, 0, stream>>>(ypre, yv);

    // out := bias terms (l_out_b bias + yv-weighted l_out_w biases)
    k_init_out<<<(B_N * 64) / 256, 256, 0, stream>>>(yv, b_out, out);

    // Stage 3: out += sum_h' yv_h' * (h @ W2_h'^T)
    k_pgemm<1><<<208, 512, 0, stream>>>(hb, Wb, yv, out);
}